// Round 22
// baseline (165.299 us; speedup 1.0000x reference)
//
#include <hip/hip_runtime.h>
#include <math.h>

#define B_   16
#define T_   3072
#define D_   256
#define G_   1024
#define BT_  (B_*T_)            // 49152
#define MROWS 32                // rows per block (MFMA path)
#define QSTRIDE 1040            // u8 qu LDS row stride (16B-aligned, +16 pad)
#define RPB  16                 // rows per block (fallback path)
#define NCAND 32                // max refine candidates per row
#define MARGIN 1.0f             // d2 ambiguity margin (1-term bf16 err ~0.12 worst)
#define MARGIN_FB 0.05f         // fallback (f32 GEMM) margin

// output layout (float elements)
#define OFF_SOMZ 0ULL
#define OFF_Q    12582912ULL
#define OFF_BMU  62914560ULL
#define OFF_KC   62963712ULL

typedef __attribute__((ext_vector_type(8))) short short8;
typedef __attribute__((ext_vector_type(4))) float f32x4;
typedef unsigned long long u64;

__device__ __forceinline__ unsigned short f2bf(float f) {
    unsigned u = __float_as_uint(f);
    return (unsigned short)((u + 0x7FFFu + ((u >> 16) & 1u)) >> 16);   // RNE
}
__device__ __forceinline__ float bf2f(unsigned short h) {
    return __uint_as_float(((unsigned)h) << 16);
}

// ---------------- kernel A: nodes -> B-frag bf16 + ||n||^2 (f32 + f64) ----------------
// Verified r11-r21: B frag lane l holds B[k=ks*32+8*(l>>4)+i][col=nt*16+(l&15)].
__global__ __launch_bounds__(256) void prep_mx(const float* __restrict__ nodes,
                                               short* __restrict__ bh,
                                               float* __restrict__ nsq,
                                               double* __restrict__ nsq64) {
    const int tid = threadIdx.x;
    const int c   = blockIdx.x * 4 + (tid >> 6);   // col (node)
    const int j   = tid & 31;                       // 8-elem k-chunk
    const int sel = (tid >> 5) & 1;
    if (sel == 0) {
        const float4* np4 = (const float4*)(nodes + (size_t)c * D_);
        float4 v0 = np4[j * 2 + 0];
        float4 v1 = np4[j * 2 + 1];
        float f[8] = {v0.x, v0.y, v0.z, v0.w, v1.x, v1.y, v1.z, v1.w};
        short8 pk;
        #pragma unroll
        for (int i = 0; i < 8; ++i) pk[i] = (short)f2bf(f[i]);
        const int idx = ((c >> 4) * 8 + (j >> 2)) * 64 + ((c & 15) | ((j & 3) << 4));
        ((short8*)bh)[idx] = pk;
        float s = 0.f;
        #pragma unroll
        for (int i = 0; i < 8; ++i) s += f[i] * f[i];
        #pragma unroll
        for (int mk = 1; mk < 32; mk <<= 1) s += __shfl_xor(s, mk, 64);
        if (j == 0) nsq[c] = s;
    } else if (j == 0) {
        const float* nc = nodes + (size_t)c * D_;
        double s = 0.0;
        for (int k = 0; k < D_; ++k) {
            double nv = (double)nc[k];
            s = fma(nv, nv, s);
        }
        nsq64[c] = s;
    }
}

// ---------------- kernel B: 512-thread block (8 waves), 1-term MFMA, u32 keys ----------------
__global__ __launch_bounds__(512) void som_mfma(const float* __restrict__ z,
                                                const float* __restrict__ mask,
                                                const float* __restrict__ nodes,
                                                const short* __restrict__ bh_g,
                                                const float* __restrict__ nsq_g,
                                                const double* __restrict__ nsq64_g,
                                                float* __restrict__ out) {
    __shared__ unsigned char qu_l[MROWS][QSTRIDE]; // raw q, u8-quantized (33.3 KB)
    __shared__ float zsq_s[MROWS], tw_s[MROWS], mk_s[MROWS], qinv_s[MROWS], dmin2_s[MROWS];
    __shared__ int   bmu_s[MROWS], cnt_s[MROWS], cand_s[MROWS][NCAND];
    __shared__ unsigned mred[MROWS][4];
    __shared__ float qred[MROWS][4];

    const int tid  = threadIdx.x;
    const int lane = tid & 63;
    const int wave = tid >> 6;                      // 0..7
    const int mt   = wave & 1;                      // M-tile (rows mt*16..)
    const int nq   = wave >> 1;                     // N quarter: tiles [nq*16, +16)
    const int row0 = blockIdx.x * MROWS;
    const int b    = row0 / T_;                     // 3072 % 32 == 0
    const int t0   = row0 % T_;

    if (tid < MROWS) {
        int t = t0 + tid;
        mk_s[tid] = mask[b * T_ + t];
        tw_s[tid] = (float)pow((double)0.999f, (double)(T_ - 1 - t));  // f32-CR power
        cnt_s[tid] = 0;
    }
    __syncthreads();

    // ---- A-fragments (bf16 hi only), exact-f32 weighting wz = fl(fl(z*tw)*mask) ----
    const int arow_l = mt * 16 + (lane & 15);       // block-local row
    const int koff   = 8 * (lane >> 4);
    const float twl = tw_s[arow_l], mkl = mk_s[arow_l];
    const float* zrow = z + (size_t)(row0 + arow_l) * D_;
    short8 ah[8];
    float zsq_part = 0.f;
    #pragma unroll
    for (int ks = 0; ks < 8; ++ks) {
        const float4* zp4 = (const float4*)(zrow + ks * 32 + koff);
        float4 u0 = zp4[0], u1 = zp4[1];
        float f[8] = {u0.x, u0.y, u0.z, u0.w, u1.x, u1.y, u1.z, u1.w};
        short8 ph;
        #pragma unroll
        for (int i = 0; i < 8; ++i) {
            float w = __fmul_rn(__fmul_rn(f[i], twl), mkl);
            zsq_part += w * w;
            ph[i] = (short)f2bf(w);
        }
        ah[ks] = ph;
    }
    zsq_part += __shfl_xor(zsq_part, 16, 64);
    zsq_part += __shfl_xor(zsq_part, 32, 64);
    if ((lane >> 4) == 0 && nq == 0) zsq_s[arow_l] = zsq_part;
    __syncthreads();

    const int drow_base = mt * 16 + (lane >> 4) * 4;   // D rows this lane produces
    float zq[4];
    #pragma unroll
    for (int rg = 0; rg < 4; ++rg) zq[rg] = zsq_s[drow_base + rg];

    // ---- main loop: 16 N-tiles per wave (2/iter), 1-term dot = ah*bh ----
    float qs[4] = {0.f, 0.f, 0.f, 0.f};
    unsigned mn1[4] = {~0u, ~0u, ~0u, ~0u};
    unsigned mn2[4] = {~0u, ~0u, ~0u, ~0u};
    const short8* BH = (const short8*)bh_g;

    for (int nt0 = nq * 16; nt0 < nq * 16 + 16; nt0 += 2) {
        const int nt1 = nt0 + 1;
        f32x4 acc0 = {0.f, 0.f, 0.f, 0.f}, acc1 = {0.f, 0.f, 0.f, 0.f};
        #pragma unroll
        for (int ks = 0; ks < 8; ++ks) {
            short8 b0 = BH[(nt0 * 8 + ks) * 64 + lane];
            short8 b1 = BH[(nt1 * 8 + ks) * 64 + lane];
            acc0 = __builtin_amdgcn_mfma_f32_16x16x32_bf16(ah[ks], b0, acc0, 0, 0, 0);
            acc1 = __builtin_amdgcn_mfma_f32_16x16x32_bf16(ah[ks], b1, acc1, 0, 0, 0);
        }
        #pragma unroll
        for (int h = 0; h < 2; ++h) {
            const int col = (h ? nt1 : nt0) * 16 + (lane & 15);
            const float nsqc = nsq_g[col];
            f32x4 a = h ? acc1 : acc0;
            #pragma unroll
            for (int rg = 0; rg < 4; ++rg) {
                float d2   = fmaxf(zq[rg] - 2.f * a[rg] + nsqc, 1e-12f);
                float dist = __builtin_amdgcn_sqrtf(d2);
                float qu   = __builtin_amdgcn_rcpf(1.f + dist);
                qs[rg] += qu;
                unsigned pk = (__float_as_uint(d2) & ~1023u) | (unsigned)col;
                if (pk < mn1[rg]) { mn2[rg] = mn1[rg]; mn1[rg] = pk; }
                else if (pk < mn2[rg]) { mn2[rg] = pk; }
                qu_l[drow_base + rg][col] = (unsigned char)(qu * 255.f + 0.5f);
            }
        }
    }

    // ---- row reductions within wave, then merge the 4 N-quarters ----
    #pragma unroll
    for (int rg = 0; rg < 4; ++rg) {
        float q = qs[rg];
        unsigned m = mn1[rg];
        #pragma unroll
        for (int mk = 1; mk < 16; mk <<= 1) {
            q += __shfl_xor(q, mk, 64);
            unsigned o = __shfl_xor(m, mk, 64);
            m = o < m ? o : m;
        }
        if ((lane & 15) == 0) {
            int row = drow_base + rg;
            qred[row][nq] = q;
            mred[row][nq] = m;
        }
    }
    __syncthreads();

    if (tid < MROWS) {
        int r = tid;
        float q = qred[r][0] + qred[r][1] + qred[r][2] + qred[r][3];
        unsigned m = mred[r][0];
        m = mred[r][1] < m ? mred[r][1] : m;
        m = mred[r][2] < m ? mred[r][2] : m;
        m = mred[r][3] < m ? mred[r][3] : m;
        dmin2_s[r] = __uint_as_float(m & ~1023u);   // truncated min d2 (<= true)
        qinv_s[r]  = 1.f / q;
    }
    __syncthreads();

    // ---- candidate gather from per-lane top-2 (u32 keys) ----
    #pragma unroll
    for (int rg = 0; rg < 4; ++rg) {
        int row = drow_base + rg;
        float lim = dmin2_s[row] + MARGIN;
        #pragma unroll
        for (int u = 0; u < 2; ++u) {
            unsigned mm = u ? mn2[rg] : mn1[rg];
            float d2v = __uint_as_float(mm & ~1023u);
            if (d2v < lim) {
                int sl = atomicAdd(&cnt_s[row], 1);
                if (sl < NCAND) cand_s[row][sl] = (int)(mm & 1023u);
            }
        }
    }
    __syncthreads();

    // ---- normalized q write FIRST (stores drain under the f64 refine below) ----
    float4* q4 = (float4*)(out + OFF_Q + (size_t)row0 * G_);
    #pragma unroll 8
    for (int i = 0; i < 16; ++i) {
        int p = i * 512 + tid;          // 8192 float4 of 32x1024
        int row = p >> 8, g = p & 255;
        float qi255 = qinv_s[row] * (1.f / 255.f);
        uchar4 qb = *(const uchar4*)&qu_l[row][4 * g];
        float4 v;
        v.x = (float)qb.x * qi255; v.y = (float)qb.y * qi255;
        v.z = (float)qb.z * qi255; v.w = (float)qb.w * qi255;
        q4[p] = v;
    }

    // ---- f64 re-rank of the candidate set (np-f64 emulation; nsq64 precomputed) ----
    {
        const int r = tid >> 4;          // 0..31
        const int s = tid & 15;
        const int cnt = cnt_s[r] < NCAND ? cnt_s[r] : NCAND;
        const int row = row0 + r;
        const double w64 = (double)tw_s[r] * (double)mk_s[r];
        const float* zp = z + (size_t)row * D_;
        double bs = 1e300; int bc = 0x7FFFFFFF;
        for (int i = s; i < cnt; i += 16) {
            const int c = cand_s[r][i];
            const float* nc = nodes + (size_t)c * D_;
            double dot = 0.0;
            for (int k = 0; k < D_; ++k) {
                double zw = (double)zp[k] * w64;
                dot = fma(zw, (double)nc[k], dot);
            }
            double sc = nsq64_g[c] - 2.0 * dot;
            if (sc < bs || (sc == bs && c < bc)) { bs = sc; bc = c; }
        }
        #pragma unroll
        for (int mm = 1; mm < 16; mm <<= 1) {
            double os = __shfl_xor(bs, mm, 64);
            int    oc = __shfl_xor(bc, mm, 64);
            if (os < bs || (os == bs && oc < bc)) { bs = os; bc = oc; }
        }
        if (s == 0) {
            bmu_s[r] = bc;
            out[OFF_BMU + row]       = (float)bc;
            out[OFF_KC + 2*row]      = (float)(bc >> 5);
            out[OFF_KC + 2*row + 1]  = (float)(bc & 31);
        }
    }
    __syncthreads();

    // ---- som_z = z + 0.1*(nodes[bmu] - z)*mask ----
    const float4* zr4 = (const float4*)(z + (size_t)row0 * D_);
    float4* so4 = (float4*)(out + OFF_SOMZ + (size_t)row0 * D_);
    #pragma unroll 4
    for (int i = 0; i < 4; ++i) {
        int p  = i * 512 + tid;         // 2048 float4 of 32x256
        int r  = p >> 6;
        int k4 = p & 63;
        float4 zv = zr4[p];
        float4 nn = ((const float4*)(nodes + (size_t)bmu_s[r] * D_))[k4];
        float m = 0.1f * mk_s[r];
        float4 o;
        o.x = zv.x + m * (nn.x - zv.x);
        o.y = zv.y + m * (nn.y - zv.y);
        o.z = zv.z + m * (nn.z - zv.z);
        o.w = zv.w + m * (nn.w - zv.w);
        so4[p] = o;
    }
}

// ---------------- fallback (round-10 verified f32 path, no workspace) ----------------
#define ROWS16(M) M(0) M(1) M(2) M(3) M(4) M(5) M(6) M(7) \
                  M(8) M(9) M(10) M(11) M(12) M(13) M(14) M(15)

__device__ __forceinline__ float qcomp_fb(float zq, float dot, float nsq,
                                          u64& mn, int col) {
    float d2   = zq - 2.f * dot + nsq;
    float dist = sqrtf(fmaxf(d2, 1e-12f));
    u64 pk = ((u64)__float_as_uint(dist) << 32) | (unsigned)col;
    mn = pk < mn ? pk : mn;
    return 1.f / (1.f + dist);
}

__global__ void som_fb(const float* __restrict__ z,
                       const float* __restrict__ mask,
                       const float* __restrict__ nodes,
                       float* __restrict__ out) {
    __shared__ __align__(16) float zl[RPB][D_];
    __shared__ float zsq_s[RPB], mk_s[RPB], tw_s[RPB], qinv_s[RPB], dmin2_s[RPB];
    __shared__ int   bmu_s[RPB], cnt_s[RPB], cand_s[RPB][NCAND];
    __shared__ u64   mred[RPB][4];
    __shared__ float qred[RPB][4];

    const int tid  = threadIdx.x;
    const int lane = tid & 63;
    const int wave = tid >> 6;
    const int row0 = blockIdx.x * RPB;
    const int b    = row0 / T_;
    const int t0   = row0 % T_;

    if (tid < RPB) {
        int t = t0 + tid;
        mk_s[tid] = mask[b * T_ + t];
        tw_s[tid] = (float)pow((double)0.999f, (double)(T_ - 1 - t));
        cnt_s[tid] = 0;
    }
    __syncthreads();

    const float4* z4 = (const float4*)(z + (size_t)row0 * D_);
    float4* zl4 = (float4*)zl;
    #pragma unroll
    for (int i = 0; i < 4; ++i) {
        int p = i * 256 + tid;
        int r = p >> 6;
        float tw = tw_s[r], m = mk_s[r];
        float4 v = z4[p];
        v.x = __fmul_rn(__fmul_rn(v.x, tw), m);
        v.y = __fmul_rn(__fmul_rn(v.y, tw), m);
        v.z = __fmul_rn(__fmul_rn(v.z, tw), m);
        v.w = __fmul_rn(__fmul_rn(v.w, tw), m);
        zl4[p] = v;
        float s = v.x*v.x + v.y*v.y + v.z*v.z + v.w*v.w;
        #pragma unroll
        for (int mm = 32; mm; mm >>= 1) s += __shfl_xor(s, mm, 64);
        if (lane == 0) zsq_s[r] = s;
    }
    __syncthreads();

#define DECL_ACC(i) float4 a##i = {0.f, 0.f, 0.f, 0.f};
    ROWS16(DECL_ACC)
#undef DECL_ACC
    float4 nss = {0.f, 0.f, 0.f, 0.f};
    const float4* nd4 = (const float4*)nodes;
    for (int k4 = 0; k4 < 64; ++k4) {
        float4 c0 = nd4[(4*tid + 0) * 64 + k4];
        float4 c1 = nd4[(4*tid + 1) * 64 + k4];
        float4 c2 = nd4[(4*tid + 2) * 64 + k4];
        float4 c3 = nd4[(4*tid + 3) * 64 + k4];
        nss.x += c0.x*c0.x + c0.y*c0.y + c0.z*c0.z + c0.w*c0.w;
        nss.y += c1.x*c1.x + c1.y*c1.y + c1.z*c1.z + c1.w*c1.w;
        nss.z += c2.x*c2.x + c2.y*c2.y + c2.z*c2.z + c2.w*c2.w;
        nss.w += c3.x*c3.x + c3.y*c3.y + c3.z*c3.z + c3.w*c3.w;
#define RFB(i) { float4 zv = zl4[(i) * 64 + k4];                                              \
        a##i.x = fmaf(zv.x, c0.x, fmaf(zv.y, c0.y, fmaf(zv.z, c0.z, fmaf(zv.w, c0.w, a##i.x)))); \
        a##i.y = fmaf(zv.x, c1.x, fmaf(zv.y, c1.y, fmaf(zv.z, c1.z, fmaf(zv.w, c1.w, a##i.y)))); \
        a##i.z = fmaf(zv.x, c2.x, fmaf(zv.y, c2.y, fmaf(zv.z, c2.z, fmaf(zv.w, c2.w, a##i.z)))); \
        a##i.w = fmaf(zv.x, c3.x, fmaf(zv.y, c3.y, fmaf(zv.z, c3.z, fmaf(zv.w, c3.w, a##i.w)))); }
        ROWS16(RFB)
#undef RFB
    }

#define EPI(i) { float zq = zsq_s[i]; u64 mn = ~0ULL;                       \
        a##i.x = qcomp_fb(zq, a##i.x, nss.x, mn, 4*tid + 0);                \
        a##i.y = qcomp_fb(zq, a##i.y, nss.y, mn, 4*tid + 1);                \
        a##i.z = qcomp_fb(zq, a##i.z, nss.z, mn, 4*tid + 2);                \
        a##i.w = qcomp_fb(zq, a##i.w, nss.w, mn, 4*tid + 3);                \
        float qs = a##i.x + a##i.y + a##i.z + a##i.w;                       \
        _Pragma("unroll")                                                   \
        for (int mm = 32; mm; mm >>= 1) {                                   \
            qs += __shfl_xor(qs, mm, 64);                                   \
            u64 o1 = __shfl_xor(mn, mm, 64);                                \
            mn = o1 < mn ? o1 : mn;                                         \
        }                                                                   \
        if (lane == 0) { qred[i][wave] = qs; mred[i][wave] = mn; } }
    ROWS16(EPI)
#undef EPI
    __syncthreads();

    if (tid < RPB) {
        int r = tid;
        float qs = qred[r][0] + qred[r][1] + qred[r][2] + qred[r][3];
        u64 mn1 = mred[r][0];
        mn1 = mred[r][1] < mn1 ? mred[r][1] : mn1;
        mn1 = mred[r][2] < mn1 ? mred[r][2] : mn1;
        mn1 = mred[r][3] < mn1 ? mred[r][3] : mn1;
        float dmin = __uint_as_float((unsigned)(mn1 >> 32));
        dmin2_s[r] = dmin * dmin;
        qinv_s[r]  = 1.f / qs;
    }
    __syncthreads();

#define GC(QU, COL, LIM, RI) { float dr = 1.f / (QU) - 1.f;                 \
        if (dr * dr < (LIM)) { int sl = atomicAdd(&cnt_s[RI], 1);           \
            if (sl < NCAND) cand_s[RI][sl] = (COL); } }
#define GTH(i) { float lim = dmin2_s[i] + MARGIN_FB;                        \
        GC(a##i.x, 4*tid + 0, lim, i) GC(a##i.y, 4*tid + 1, lim, i)         \
        GC(a##i.z, 4*tid + 2, lim, i) GC(a##i.w, 4*tid + 3, lim, i) }
    ROWS16(GTH)
#undef GTH
#undef GC

    float4* q4 = (float4*)(out + OFF_Q + (size_t)row0 * G_);
#define WRQ(i) { float qi = qinv_s[i]; float4 v;                            \
        v.x = a##i.x * qi; v.y = a##i.y * qi;                               \
        v.z = a##i.z * qi; v.w = a##i.w * qi;                               \
        q4[(i) * 256 + tid] = v; }
    ROWS16(WRQ)
#undef WRQ
    __syncthreads();

    {
        const int r = tid >> 4;
        const int s = tid & 15;
        const int cnt = cnt_s[r] < NCAND ? cnt_s[r] : NCAND;
        const int row = row0 + r;
        const double w64 = (double)tw_s[r] * (double)mk_s[r];
        const float* zp = z + (size_t)row * D_;
        double bs = 1e300; int bc = 0x7FFFFFFF;
        for (int i = s; i < cnt; i += 16) {
            const int c = cand_s[r][i];
            const float* nc = nodes + (size_t)c * D_;
            double dot = 0.0, nsqd = 0.0;
            for (int k = 0; k < D_; ++k) {
                double zw = (double)zp[k] * w64;
                double nv = (double)nc[k];
                dot  = fma(zw, nv, dot);
                nsqd = fma(nv, nv, nsqd);
            }
            double sc = nsqd - 2.0 * dot;
            if (sc < bs || (sc == bs && c < bc)) { bs = sc; bc = c; }
        }
        #pragma unroll
        for (int mm = 1; mm < 16; mm <<= 1) {
            double os = __shfl_xor(bs, mm, 64);
            int    oc = __shfl_xor(bc, mm, 64);
            if (os < bs || (os == bs && oc < bc)) { bs = os; bc = oc; }
        }
        if (s == 0) {
            bmu_s[r] = bc;
            out[OFF_BMU + row]       = (float)bc;
            out[OFF_KC + 2*row]      = (float)(bc >> 5);
            out[OFF_KC + 2*row + 1]  = (float)(bc & 31);
        }
    }
    __syncthreads();

    const float4* zr4 = (const float4*)(z + (size_t)row0 * D_);
    float4* so4 = (float4*)(out + OFF_SOMZ + (size_t)row0 * D_);
    #pragma unroll
    for (int i = 0; i < 4; ++i) {
        int p  = i * 256 + tid;
        int r  = p >> 6;
        int k4 = p & 63;
        float4 zv = zr4[p];
        float4 nn = ((const float4*)(nodes + (size_t)bmu_s[r] * D_))[k4];
        float m = 0.1f * mk_s[r];
        float4 o;
        o.x = zv.x + m * (nn.x - zv.x);
        o.y = zv.y + m * (nn.y - zv.y);
        o.z = zv.z + m * (nn.z - zv.z);
        o.w = zv.w + m * (nn.w - zv.w);
        so4[p] = o;
    }
}

extern "C" void kernel_launch(void* const* d_in, const int* in_sizes, int n_in,
                              void* d_out, int out_size, void* d_ws, size_t ws_size,
                              hipStream_t stream) {
    const float* z     = (const float*)d_in[0];
    const float* mask  = (const float*)d_in[1];
    const float* nodes = (const float*)d_in[2];
    float* out = (float*)d_out;

    const size_t bh_bytes = (size_t)G_ * D_ * 2;            // 512 KB
    const size_t n64_off  = bh_bytes;                        // 8-byte aligned
    const size_t n32_off  = n64_off + (size_t)G_ * sizeof(double);
    const size_t need     = n32_off + (size_t)G_ * sizeof(float);   // ~524 KB
    if (ws_size >= need) {
        short*  bh    = (short*)d_ws;
        double* nsq64 = (double*)((char*)d_ws + n64_off);
        float*  nsq   = (float*)((char*)d_ws + n32_off);
        prep_mx<<<G_ / 4, 256, 0, stream>>>(nodes, bh, nsq, nsq64);
        som_mfma<<<BT_ / MROWS, 512, 0, stream>>>(z, mask, nodes, bh, nsq, nsq64, out);
    } else {
        som_fb<<<BT_ / RPB, 256, 0, stream>>>(z, mask, nodes, out);
    }
}

// Round 23
// 159.201 us; speedup vs baseline: 1.0383x; 1.0383x over previous
//
#include <hip/hip_runtime.h>
#include <math.h>

#define B_   16
#define T_   3072
#define D_   256
#define G_   1024
#define BT_  (B_*T_)            // 49152
#define MROWS 16                // rows per block (MFMA path): 1 M-tile, 4 N-quarter waves
#define QSTRIDE 1040            // u8 qu LDS row stride (16B-aligned, +16 pad)
#define RPB  16                 // rows per block (fallback path)
#define NCAND 32                // max refine candidates per row
#define MARGIN 1.0f             // d2 ambiguity margin (1-term bf16 err ~0.12 worst)
#define MARGIN_FB 0.05f         // fallback (f32 GEMM) margin

// output layout (float elements)
#define OFF_SOMZ 0ULL
#define OFF_Q    12582912ULL
#define OFF_BMU  62914560ULL
#define OFF_KC   62963712ULL

typedef __attribute__((ext_vector_type(8))) short short8;
typedef __attribute__((ext_vector_type(4))) float f32x4;
typedef unsigned long long u64;

__device__ __forceinline__ unsigned short f2bf(float f) {
    unsigned u = __float_as_uint(f);
    return (unsigned short)((u + 0x7FFFu + ((u >> 16) & 1u)) >> 16);   // RNE
}
__device__ __forceinline__ float bf2f(unsigned short h) {
    return __uint_as_float(((unsigned)h) << 16);
}

// ---------------- kernel A: nodes -> B-frag bf16 + ||n||^2 (f32 + f64) ----------------
// Verified r11-r22: B frag lane l holds B[k=ks*32+8*(l>>4)+i][col=nt*16+(l&15)].
__global__ __launch_bounds__(256) void prep_mx(const float* __restrict__ nodes,
                                               short* __restrict__ bh,
                                               float* __restrict__ nsq,
                                               double* __restrict__ nsq64) {
    const int tid = threadIdx.x;
    const int c   = blockIdx.x * 4 + (tid >> 6);   // col (node)
    const int j   = tid & 31;                       // 8-elem k-chunk
    const int sel = (tid >> 5) & 1;
    if (sel == 0) {
        const float4* np4 = (const float4*)(nodes + (size_t)c * D_);
        float4 v0 = np4[j * 2 + 0];
        float4 v1 = np4[j * 2 + 1];
        float f[8] = {v0.x, v0.y, v0.z, v0.w, v1.x, v1.y, v1.z, v1.w};
        short8 pk;
        #pragma unroll
        for (int i = 0; i < 8; ++i) pk[i] = (short)f2bf(f[i]);
        const int idx = ((c >> 4) * 8 + (j >> 2)) * 64 + ((c & 15) | ((j & 3) << 4));
        ((short8*)bh)[idx] = pk;
        float s = 0.f;
        #pragma unroll
        for (int i = 0; i < 8; ++i) s += f[i] * f[i];
        #pragma unroll
        for (int mk = 1; mk < 32; mk <<= 1) s += __shfl_xor(s, mk, 64);
        if (j == 0) nsq[c] = s;
    } else if (j == 0) {
        const float* nc = nodes + (size_t)c * D_;
        double s = 0.0;
        for (int k = 0; k < D_; ++k) {
            double nv = (double)nc[k];
            s = fma(nv, nv, s);
        }
        nsq64[c] = s;
    }
}

// ---------------- kernel B: 16-row block, 4 N-quarter waves, 1-term MFMA ----------------
__global__ __launch_bounds__(256) void som_mfma(const float* __restrict__ z,
                                                const float* __restrict__ mask,
                                                const float* __restrict__ nodes,
                                                const short* __restrict__ bh_g,
                                                const float* __restrict__ nsq_g,
                                                const double* __restrict__ nsq64_g,
                                                float* __restrict__ out) {
    __shared__ unsigned char qu_l[MROWS][QSTRIDE]; // raw q, u8-quantized (16.6 KB)
    __shared__ float zsq_s[MROWS], tw_s[MROWS], mk_s[MROWS], qinv_s[MROWS], dmin2_s[MROWS];
    __shared__ int   bmu_s[MROWS], cnt_s[MROWS], cand_s[MROWS][NCAND];
    __shared__ unsigned mred[MROWS][4];
    __shared__ float qred[MROWS][4];

    const int tid  = threadIdx.x;
    const int lane = tid & 63;
    const int wave = tid >> 6;                      // 0..3 = N quarter
    const int nq   = wave;                          // tiles [nq*16, +16)
    const int row0 = blockIdx.x * MROWS;
    const int b    = row0 / T_;                     // 3072 % 16 == 0
    const int t0   = row0 % T_;

    if (tid < MROWS) {
        int t = t0 + tid;
        mk_s[tid] = mask[b * T_ + t];
        tw_s[tid] = (float)pow((double)0.999f, (double)(T_ - 1 - t));  // f32-CR power
        cnt_s[tid] = 0;
    }
    __syncthreads();

    // ---- A-fragments (bf16 hi only), exact-f32 weighting wz = fl(fl(z*tw)*mask) ----
    const int arow_l = lane & 15;                   // block-local row
    const int koff   = 8 * (lane >> 4);
    const float twl = tw_s[arow_l], mkl = mk_s[arow_l];
    const float* zrow = z + (size_t)(row0 + arow_l) * D_;
    short8 ah[8];
    float zsq_part = 0.f;
    #pragma unroll
    for (int ks = 0; ks < 8; ++ks) {
        const float4* zp4 = (const float4*)(zrow + ks * 32 + koff);
        float4 u0 = zp4[0], u1 = zp4[1];
        float f[8] = {u0.x, u0.y, u0.z, u0.w, u1.x, u1.y, u1.z, u1.w};
        short8 ph;
        #pragma unroll
        for (int i = 0; i < 8; ++i) {
            float w = __fmul_rn(__fmul_rn(f[i], twl), mkl);
            zsq_part += w * w;
            ph[i] = (short)f2bf(w);
        }
        ah[ks] = ph;
    }
    zsq_part += __shfl_xor(zsq_part, 16, 64);
    zsq_part += __shfl_xor(zsq_part, 32, 64);
    if ((lane >> 4) == 0 && nq == 0) zsq_s[arow_l] = zsq_part;
    __syncthreads();

    const int drow_base = (lane >> 4) * 4;          // D rows this lane produces
    float zq[4];
    #pragma unroll
    for (int rg = 0; rg < 4; ++rg) zq[rg] = zsq_s[drow_base + rg];

    // ---- main loop: 16 N-tiles per wave (2/iter), 1-term dot = ah*bh ----
    float qs[4] = {0.f, 0.f, 0.f, 0.f};
    unsigned mn1[4] = {~0u, ~0u, ~0u, ~0u};
    unsigned mn2[4] = {~0u, ~0u, ~0u, ~0u};
    const short8* BH = (const short8*)bh_g;

    for (int nt0 = nq * 16; nt0 < nq * 16 + 16; nt0 += 2) {
        const int nt1 = nt0 + 1;
        f32x4 acc0 = {0.f, 0.f, 0.f, 0.f}, acc1 = {0.f, 0.f, 0.f, 0.f};
        #pragma unroll
        for (int ks = 0; ks < 8; ++ks) {
            short8 b0 = BH[(nt0 * 8 + ks) * 64 + lane];
            short8 b1 = BH[(nt1 * 8 + ks) * 64 + lane];
            acc0 = __builtin_amdgcn_mfma_f32_16x16x32_bf16(ah[ks], b0, acc0, 0, 0, 0);
            acc1 = __builtin_amdgcn_mfma_f32_16x16x32_bf16(ah[ks], b1, acc1, 0, 0, 0);
        }
        #pragma unroll
        for (int h = 0; h < 2; ++h) {
            const int col = (h ? nt1 : nt0) * 16 + (lane & 15);
            const float nsqc = nsq_g[col];
            f32x4 a = h ? acc1 : acc0;
            #pragma unroll
            for (int rg = 0; rg < 4; ++rg) {
                float d2   = fmaxf(zq[rg] - 2.f * a[rg] + nsqc, 1e-12f);
                float dist = __builtin_amdgcn_sqrtf(d2);
                float qu   = __builtin_amdgcn_rcpf(1.f + dist);
                qs[rg] += qu;
                unsigned pk = (__float_as_uint(d2) & ~1023u) | (unsigned)col;
                if (pk < mn1[rg]) { mn2[rg] = mn1[rg]; mn1[rg] = pk; }
                else if (pk < mn2[rg]) { mn2[rg] = pk; }
                qu_l[drow_base + rg][col] = (unsigned char)(qu * 255.f + 0.5f);
            }
        }
    }

    // ---- row reductions within wave, then merge the 4 N-quarters ----
    #pragma unroll
    for (int rg = 0; rg < 4; ++rg) {
        float q = qs[rg];
        unsigned m = mn1[rg];
        #pragma unroll
        for (int mk = 1; mk < 16; mk <<= 1) {
            q += __shfl_xor(q, mk, 64);
            unsigned o = __shfl_xor(m, mk, 64);
            m = o < m ? o : m;
        }
        if ((lane & 15) == 0) {
            int row = drow_base + rg;
            qred[row][nq] = q;
            mred[row][nq] = m;
        }
    }
    __syncthreads();

    if (tid < MROWS) {
        int r = tid;
        float q = qred[r][0] + qred[r][1] + qred[r][2] + qred[r][3];
        unsigned m = mred[r][0];
        m = mred[r][1] < m ? mred[r][1] : m;
        m = mred[r][2] < m ? mred[r][2] : m;
        m = mred[r][3] < m ? mred[r][3] : m;
        dmin2_s[r] = __uint_as_float(m & ~1023u);   // truncated min d2 (<= true)
        qinv_s[r]  = 1.f / q;
    }
    __syncthreads();

    // ---- candidate gather from per-lane top-2 (u32 keys) ----
    #pragma unroll
    for (int rg = 0; rg < 4; ++rg) {
        int row = drow_base + rg;
        float lim = dmin2_s[row] + MARGIN;
        #pragma unroll
        for (int u = 0; u < 2; ++u) {
            unsigned mm = u ? mn2[rg] : mn1[rg];
            float d2v = __uint_as_float(mm & ~1023u);
            if (d2v < lim) {
                int sl = atomicAdd(&cnt_s[row], 1);
                if (sl < NCAND) cand_s[row][sl] = (int)(mm & 1023u);
            }
        }
    }
    __syncthreads();

    // ---- normalized q write FIRST (stores drain under the f64 refine below) ----
    float4* q4 = (float4*)(out + OFF_Q + (size_t)row0 * G_);
    #pragma unroll 8
    for (int i = 0; i < 16; ++i) {
        int p = i * 256 + tid;          // 4096 float4 of 16x1024
        int row = p >> 8, g = p & 255;
        float qi255 = qinv_s[row] * (1.f / 255.f);
        uchar4 qb = *(const uchar4*)&qu_l[row][4 * g];
        float4 v;
        v.x = (float)qb.x * qi255; v.y = (float)qb.y * qi255;
        v.z = (float)qb.z * qi255; v.w = (float)qb.w * qi255;
        q4[p] = v;
    }

    // ---- f64 re-rank of the candidate set (np-f64 emulation; nsq64 precomputed) ----
    {
        const int r = tid >> 4;          // 0..15
        const int s = tid & 15;
        const int cnt = cnt_s[r] < NCAND ? cnt_s[r] : NCAND;
        const int row = row0 + r;
        const double w64 = (double)tw_s[r] * (double)mk_s[r];
        const float* zp = z + (size_t)row * D_;
        double bs = 1e300; int bc = 0x7FFFFFFF;
        for (int i = s; i < cnt; i += 16) {
            const int c = cand_s[r][i];
            const float* nc = nodes + (size_t)c * D_;
            double dot = 0.0;
            for (int k = 0; k < D_; ++k) {
                double zw = (double)zp[k] * w64;
                dot = fma(zw, (double)nc[k], dot);
            }
            double sc = nsq64_g[c] - 2.0 * dot;
            if (sc < bs || (sc == bs && c < bc)) { bs = sc; bc = c; }
        }
        #pragma unroll
        for (int mm = 1; mm < 16; mm <<= 1) {
            double os = __shfl_xor(bs, mm, 64);
            int    oc = __shfl_xor(bc, mm, 64);
            if (os < bs || (os == bs && oc < bc)) { bs = os; bc = oc; }
        }
        if (s == 0) {
            bmu_s[r] = bc;
            out[OFF_BMU + row]       = (float)bc;
            out[OFF_KC + 2*row]      = (float)(bc >> 5);
            out[OFF_KC + 2*row + 1]  = (float)(bc & 31);
        }
    }
    __syncthreads();

    // ---- som_z = z + 0.1*(nodes[bmu] - z)*mask ----
    const float4* zr4 = (const float4*)(z + (size_t)row0 * D_);
    float4* so4 = (float4*)(out + OFF_SOMZ + (size_t)row0 * D_);
    #pragma unroll
    for (int i = 0; i < 4; ++i) {
        int p  = i * 256 + tid;         // 1024 float4 of 16x256
        int r  = p >> 6;
        int k4 = p & 63;
        float4 zv = zr4[p];
        float4 nn = ((const float4*)(nodes + (size_t)bmu_s[r] * D_))[k4];
        float m = 0.1f * mk_s[r];
        float4 o;
        o.x = zv.x + m * (nn.x - zv.x);
        o.y = zv.y + m * (nn.y - zv.y);
        o.z = zv.z + m * (nn.z - zv.z);
        o.w = zv.w + m * (nn.w - zv.w);
        so4[p] = o;
    }
}

// ---------------- fallback (round-10 verified f32 path, no workspace) ----------------
#define ROWS16(M) M(0) M(1) M(2) M(3) M(4) M(5) M(6) M(7) \
                  M(8) M(9) M(10) M(11) M(12) M(13) M(14) M(15)

__device__ __forceinline__ float qcomp_fb(float zq, float dot, float nsq,
                                          u64& mn, int col) {
    float d2   = zq - 2.f * dot + nsq;
    float dist = sqrtf(fmaxf(d2, 1e-12f));
    u64 pk = ((u64)__float_as_uint(dist) << 32) | (unsigned)col;
    mn = pk < mn ? pk : mn;
    return 1.f / (1.f + dist);
}

__global__ void som_fb(const float* __restrict__ z,
                       const float* __restrict__ mask,
                       const float* __restrict__ nodes,
                       float* __restrict__ out) {
    __shared__ __align__(16) float zl[RPB][D_];
    __shared__ float zsq_s[RPB], mk_s[RPB], tw_s[RPB], qinv_s[RPB], dmin2_s[RPB];
    __shared__ int   bmu_s[RPB], cnt_s[RPB], cand_s[RPB][NCAND];
    __shared__ u64   mred[RPB][4];
    __shared__ float qred[RPB][4];

    const int tid  = threadIdx.x;
    const int lane = tid & 63;
    const int wave = tid >> 6;
    const int row0 = blockIdx.x * RPB;
    const int b    = row0 / T_;
    const int t0   = row0 % T_;

    if (tid < RPB) {
        int t = t0 + tid;
        mk_s[tid] = mask[b * T_ + t];
        tw_s[tid] = (float)pow((double)0.999f, (double)(T_ - 1 - t));
        cnt_s[tid] = 0;
    }
    __syncthreads();

    const float4* z4 = (const float4*)(z + (size_t)row0 * D_);
    float4* zl4 = (float4*)zl;
    #pragma unroll
    for (int i = 0; i < 4; ++i) {
        int p = i * 256 + tid;
        int r = p >> 6;
        float tw = tw_s[r], m = mk_s[r];
        float4 v = z4[p];
        v.x = __fmul_rn(__fmul_rn(v.x, tw), m);
        v.y = __fmul_rn(__fmul_rn(v.y, tw), m);
        v.z = __fmul_rn(__fmul_rn(v.z, tw), m);
        v.w = __fmul_rn(__fmul_rn(v.w, tw), m);
        zl4[p] = v;
        float s = v.x*v.x + v.y*v.y + v.z*v.z + v.w*v.w;
        #pragma unroll
        for (int mm = 32; mm; mm >>= 1) s += __shfl_xor(s, mm, 64);
        if (lane == 0) zsq_s[r] = s;
    }
    __syncthreads();

#define DECL_ACC(i) float4 a##i = {0.f, 0.f, 0.f, 0.f};
    ROWS16(DECL_ACC)
#undef DECL_ACC
    float4 nss = {0.f, 0.f, 0.f, 0.f};
    const float4* nd4 = (const float4*)nodes;
    for (int k4 = 0; k4 < 64; ++k4) {
        float4 c0 = nd4[(4*tid + 0) * 64 + k4];
        float4 c1 = nd4[(4*tid + 1) * 64 + k4];
        float4 c2 = nd4[(4*tid + 2) * 64 + k4];
        float4 c3 = nd4[(4*tid + 3) * 64 + k4];
        nss.x += c0.x*c0.x + c0.y*c0.y + c0.z*c0.z + c0.w*c0.w;
        nss.y += c1.x*c1.x + c1.y*c1.y + c1.z*c1.z + c1.w*c1.w;
        nss.z += c2.x*c2.x + c2.y*c2.y + c2.z*c2.z + c2.w*c2.w;
        nss.w += c3.x*c3.x + c3.y*c3.y + c3.z*c3.z + c3.w*c3.w;
#define RFB(i) { float4 zv = zl4[(i) * 64 + k4];                                              \
        a##i.x = fmaf(zv.x, c0.x, fmaf(zv.y, c0.y, fmaf(zv.z, c0.z, fmaf(zv.w, c0.w, a##i.x)))); \
        a##i.y = fmaf(zv.x, c1.x, fmaf(zv.y, c1.y, fmaf(zv.z, c1.z, fmaf(zv.w, c1.w, a##i.y)))); \
        a##i.z = fmaf(zv.x, c2.x, fmaf(zv.y, c2.y, fmaf(zv.z, c2.z, fmaf(zv.w, c2.w, a##i.z)))); \
        a##i.w = fmaf(zv.x, c3.x, fmaf(zv.y, c3.y, fmaf(zv.z, c3.z, fmaf(zv.w, c3.w, a##i.w)))); }
        ROWS16(RFB)
#undef RFB
    }

#define EPI(i) { float zq = zsq_s[i]; u64 mn = ~0ULL;                       \
        a##i.x = qcomp_fb(zq, a##i.x, nss.x, mn, 4*tid + 0);                \
        a##i.y = qcomp_fb(zq, a##i.y, nss.y, mn, 4*tid + 1);                \
        a##i.z = qcomp_fb(zq, a##i.z, nss.z, mn, 4*tid + 2);                \
        a##i.w = qcomp_fb(zq, a##i.w, nss.w, mn, 4*tid + 3);                \
        float qs = a##i.x + a##i.y + a##i.z + a##i.w;                       \
        _Pragma("unroll")                                                   \
        for (int mm = 32; mm; mm >>= 1) {                                   \
            qs += __shfl_xor(qs, mm, 64);                                   \
            u64 o1 = __shfl_xor(mn, mm, 64);                                \
            mn = o1 < mn ? o1 : mn;                                         \
        }                                                                   \
        if (lane == 0) { qred[i][wave] = qs; mred[i][wave] = mn; } }
    ROWS16(EPI)
#undef EPI
    __syncthreads();

    if (tid < RPB) {
        int r = tid;
        float qs = qred[r][0] + qred[r][1] + qred[r][2] + qred[r][3];
        u64 mn1 = mred[r][0];
        mn1 = mred[r][1] < mn1 ? mred[r][1] : mn1;
        mn1 = mred[r][2] < mn1 ? mred[r][2] : mn1;
        mn1 = mred[r][3] < mn1 ? mred[r][3] : mn1;
        float dmin = __uint_as_float((unsigned)(mn1 >> 32));
        dmin2_s[r] = dmin * dmin;
        qinv_s[r]  = 1.f / qs;
    }
    __syncthreads();

#define GC(QU, COL, LIM, RI) { float dr = 1.f / (QU) - 1.f;                 \
        if (dr * dr < (LIM)) { int sl = atomicAdd(&cnt_s[RI], 1);           \
            if (sl < NCAND) cand_s[RI][sl] = (COL); } }
#define GTH(i) { float lim = dmin2_s[i] + MARGIN_FB;                        \
        GC(a##i.x, 4*tid + 0, lim, i) GC(a##i.y, 4*tid + 1, lim, i)         \
        GC(a##i.z, 4*tid + 2, lim, i) GC(a##i.w, 4*tid + 3, lim, i) }
    ROWS16(GTH)
#undef GTH
#undef GC

    float4* q4 = (float4*)(out + OFF_Q + (size_t)row0 * G_);
#define WRQ(i) { float qi = qinv_s[i]; float4 v;                            \
        v.x = a##i.x * qi; v.y = a##i.y * qi;                               \
        v.z = a##i.z * qi; v.w = a##i.w * qi;                               \
        q4[(i) * 256 + tid] = v; }
    ROWS16(WRQ)
#undef WRQ
    __syncthreads();

    {
        const int r = tid >> 4;
        const int s = tid & 15;
        const int cnt = cnt_s[r] < NCAND ? cnt_s[r] : NCAND;
        const int row = row0 + r;
        const double w64 = (double)tw_s[r] * (double)mk_s[r];
        const float* zp = z + (size_t)row * D_;
        double bs = 1e300; int bc = 0x7FFFFFFF;
        for (int i = s; i < cnt; i += 16) {
            const int c = cand_s[r][i];
            const float* nc = nodes + (size_t)c * D_;
            double dot = 0.0, nsqd = 0.0;
            for (int k = 0; k < D_; ++k) {
                double zw = (double)zp[k] * w64;
                double nv = (double)nc[k];
                dot  = fma(zw, nv, dot);
                nsqd = fma(nv, nv, nsqd);
            }
            double sc = nsqd - 2.0 * dot;
            if (sc < bs || (sc == bs && c < bc)) { bs = sc; bc = c; }
        }
        #pragma unroll
        for (int mm = 1; mm < 16; mm <<= 1) {
            double os = __shfl_xor(bs, mm, 64);
            int    oc = __shfl_xor(bc, mm, 64);
            if (os < bs || (os == bs && oc < bc)) { bs = os; bc = oc; }
        }
        if (s == 0) {
            bmu_s[r] = bc;
            out[OFF_BMU + row]       = (float)bc;
            out[OFF_KC + 2*row]      = (float)(bc >> 5);
            out[OFF_KC + 2*row + 1]  = (float)(bc & 31);
        }
    }
    __syncthreads();

    const float4* zr4 = (const float4*)(z + (size_t)row0 * D_);
    float4* so4 = (float4*)(out + OFF_SOMZ + (size_t)row0 * D_);
    #pragma unroll
    for (int i = 0; i < 4; ++i) {
        int p  = i * 256 + tid;
        int r  = p >> 6;
        int k4 = p & 63;
        float4 zv = zr4[p];
        float4 nn = ((const float4*)(nodes + (size_t)bmu_s[r] * D_))[k4];
        float m = 0.1f * mk_s[r];
        float4 o;
        o.x = zv.x + m * (nn.x - zv.x);
        o.y = zv.y + m * (nn.y - zv.y);
        o.z = zv.z + m * (nn.z - zv.z);
        o.w = zv.w + m * (nn.w - zv.w);
        so4[p] = o;
    }
}

extern "C" void kernel_launch(void* const* d_in, const int* in_sizes, int n_in,
                              void* d_out, int out_size, void* d_ws, size_t ws_size,
                              hipStream_t stream) {
    const float* z     = (const float*)d_in[0];
    const float* mask  = (const float*)d_in[1];
    const float* nodes = (const float*)d_in[2];
    float* out = (float*)d_out;

    const size_t bh_bytes = (size_t)G_ * D_ * 2;            // 512 KB
    const size_t n64_off  = bh_bytes;                        // 8-byte aligned
    const size_t n32_off  = n64_off + (size_t)G_ * sizeof(double);
    const size_t need     = n32_off + (size_t)G_ * sizeof(float);   // ~524 KB
    if (ws_size >= need) {
        short*  bh    = (short*)d_ws;
        double* nsq64 = (double*)((char*)d_ws + n64_off);
        float*  nsq   = (float*)((char*)d_ws + n32_off);
        prep_mx<<<G_ / 4, 256, 0, stream>>>(nodes, bh, nsq, nsq64);
        som_mfma<<<BT_ / MROWS, 256, 0, stream>>>(z, mask, nodes, bh, nsq, nsq64, out);
    } else {
        som_fb<<<BT_ / RPB, 256, 0, stream>>>(z, mask, nodes, out);
    }
}

// Round 24
// 140.339 us; speedup vs baseline: 1.1779x; 1.1344x over previous
//
#include <hip/hip_runtime.h>
#include <math.h>

#define B_   16
#define T_   3072
#define D_   256
#define G_   1024
#define BT_  (B_*T_)            // 49152
#define MROWS 32                // rows per block (MFMA path)
#define QSTRIDE 1040            // u8 qu LDS row stride (16B-aligned, +16 pad)
#define RPB  16                 // rows per block (fallback path)
#define NCAND 32                // max refine candidates per row
#define MARGIN 1.0f             // d2 ambiguity margin (1-term bf16 err ~0.12 worst)
#define MARGIN_FB 0.05f         // fallback (f32 GEMM) margin

// output layout (float elements)
#define OFF_SOMZ 0ULL
#define OFF_Q    12582912ULL
#define OFF_BMU  62914560ULL
#define OFF_KC   62963712ULL

typedef __attribute__((ext_vector_type(8))) short short8;
typedef __attribute__((ext_vector_type(4))) float f32x4;
typedef unsigned long long u64;

__device__ __forceinline__ unsigned short f2bf(float f) {
    unsigned u = __float_as_uint(f);
    return (unsigned short)((u + 0x7FFFu + ((u >> 16) & 1u)) >> 16);   // RNE
}
__device__ __forceinline__ float bf2f(unsigned short h) {
    return __uint_as_float(((unsigned)h) << 16);
}

// ---------------- kernel A: nodes -> B-frag bf16 + ||n||^2 (f32 + f64) ----------------
// Verified r11-r23: B frag lane l holds B[k=ks*32+8*(l>>4)+i][col=nt*16+(l&15)].
__global__ __launch_bounds__(256) void prep_mx(const float* __restrict__ nodes,
                                               short* __restrict__ bh,
                                               float* __restrict__ nsq,
                                               double* __restrict__ nsq64) {
    const int tid = threadIdx.x;
    const int c   = blockIdx.x * 4 + (tid >> 6);   // col (node)
    const int j   = tid & 31;                       // 8-elem k-chunk
    const int sel = (tid >> 5) & 1;
    if (sel == 0) {
        const float4* np4 = (const float4*)(nodes + (size_t)c * D_);
        float4 v0 = np4[j * 2 + 0];
        float4 v1 = np4[j * 2 + 1];
        float f[8] = {v0.x, v0.y, v0.z, v0.w, v1.x, v1.y, v1.z, v1.w};
        short8 pk;
        #pragma unroll
        for (int i = 0; i < 8; ++i) pk[i] = (short)f2bf(f[i]);
        const int idx = ((c >> 4) * 8 + (j >> 2)) * 64 + ((c & 15) | ((j & 3) << 4));
        ((short8*)bh)[idx] = pk;
        float s = 0.f;
        #pragma unroll
        for (int i = 0; i < 8; ++i) s += f[i] * f[i];
        #pragma unroll
        for (int mk = 1; mk < 32; mk <<= 1) s += __shfl_xor(s, mk, 64);
        if (j == 0) nsq[c] = s;
    } else if (j == 0) {
        const float* nc = nodes + (size_t)c * D_;
        double s = 0.0;
        for (int k = 0; k < D_; ++k) {
            double nv = (double)nc[k];
            s = fma(nv, nv, s);
        }
        nsq64[c] = s;
    }
}

// ---------------- kernel B: 1-term MFMA (r19 loop shape), u32 keys, approx epilogue ----------------
__global__ __launch_bounds__(256) void som_mfma(const float* __restrict__ z,
                                                const float* __restrict__ mask,
                                                const float* __restrict__ nodes,
                                                const short* __restrict__ bh_g,
                                                const float* __restrict__ nsq_g,
                                                const double* __restrict__ nsq64_g,
                                                float* __restrict__ out) {
    __shared__ unsigned char qu_l[MROWS][QSTRIDE]; // raw q, u8-quantized (33.3 KB)
    __shared__ float zsq_s[MROWS], tw_s[MROWS], mk_s[MROWS], qinv_s[MROWS], dmin2_s[MROWS];
    __shared__ int   bmu_s[MROWS], cnt_s[MROWS], cand_s[MROWS][NCAND];
    __shared__ unsigned mred[MROWS][2];
    __shared__ float qred[MROWS][2];

    const int tid  = threadIdx.x;
    const int lane = tid & 63;
    const int wave = tid >> 6;
    const int mt     = wave & 1;                    // M-tile (rows mt*16..)
    const int nthalf = wave >> 1;                   // N range [nthalf*32, +32) tiles
    const int row0 = blockIdx.x * MROWS;
    const int b    = row0 / T_;                     // 3072 % 32 == 0
    const int t0   = row0 % T_;

    if (tid < MROWS) {
        int t = t0 + tid;
        mk_s[tid] = mask[b * T_ + t];
        tw_s[tid] = (float)pow((double)0.999f, (double)(T_ - 1 - t));  // f32-CR power
        cnt_s[tid] = 0;
    }
    __syncthreads();

    // ---- A-fragments (bf16 hi only), exact-f32 weighting wz = fl(fl(z*tw)*mask) ----
    const int arow_l = mt * 16 + (lane & 15);       // block-local row
    const int koff   = 8 * (lane >> 4);
    const float twl = tw_s[arow_l], mkl = mk_s[arow_l];
    const float* zrow = z + (size_t)(row0 + arow_l) * D_;
    short8 ah[8];
    float zsq_part = 0.f;
    #pragma unroll
    for (int ks = 0; ks < 8; ++ks) {
        const float4* zp4 = (const float4*)(zrow + ks * 32 + koff);
        float4 u0 = zp4[0], u1 = zp4[1];
        float f[8] = {u0.x, u0.y, u0.z, u0.w, u1.x, u1.y, u1.z, u1.w};
        short8 ph;
        #pragma unroll
        for (int i = 0; i < 8; ++i) {
            float w = __fmul_rn(__fmul_rn(f[i], twl), mkl);
            zsq_part += w * w;
            ph[i] = (short)f2bf(w);
        }
        ah[ks] = ph;
    }
    zsq_part += __shfl_xor(zsq_part, 16, 64);
    zsq_part += __shfl_xor(zsq_part, 32, 64);
    if ((lane >> 4) == 0 && nthalf == 0) zsq_s[arow_l] = zsq_part;
    __syncthreads();

    const int drow_base = mt * 16 + (lane >> 4) * 4;   // D rows this lane produces
    float zq[4];
    #pragma unroll
    for (int rg = 0; rg < 4; ++rg) zq[rg] = zsq_s[drow_base + rg];

    // ---- main loop: r19 shape (2 N-tiles/iter), 1-term dot = ah*bh ----
    float qs[4] = {0.f, 0.f, 0.f, 0.f};
    unsigned mn1[4] = {~0u, ~0u, ~0u, ~0u};
    unsigned mn2[4] = {~0u, ~0u, ~0u, ~0u};
    const short8* BH = (const short8*)bh_g;

    for (int nt0 = nthalf * 32; nt0 < nthalf * 32 + 32; nt0 += 2) {
        const int nt1 = nt0 + 1;
        f32x4 acc0 = {0.f, 0.f, 0.f, 0.f}, acc1 = {0.f, 0.f, 0.f, 0.f};
        #pragma unroll
        for (int ks = 0; ks < 8; ++ks) {
            short8 b0 = BH[(nt0 * 8 + ks) * 64 + lane];
            short8 b1 = BH[(nt1 * 8 + ks) * 64 + lane];
            acc0 = __builtin_amdgcn_mfma_f32_16x16x32_bf16(ah[ks], b0, acc0, 0, 0, 0);
            acc1 = __builtin_amdgcn_mfma_f32_16x16x32_bf16(ah[ks], b1, acc1, 0, 0, 0);
        }
        // epilogue: approx sqrt/rcp; u32 keys = (d2bits & ~1023) | col
        #pragma unroll
        for (int h = 0; h < 2; ++h) {
            const int col = (h ? nt1 : nt0) * 16 + (lane & 15);
            const float nsqc = nsq_g[col];
            f32x4 a = h ? acc1 : acc0;
            #pragma unroll
            for (int rg = 0; rg < 4; ++rg) {
                float d2   = fmaxf(zq[rg] - 2.f * a[rg] + nsqc, 1e-12f);
                float dist = __builtin_amdgcn_sqrtf(d2);
                float qu   = __builtin_amdgcn_rcpf(1.f + dist);
                qs[rg] += qu;
                unsigned pk = (__float_as_uint(d2) & ~1023u) | (unsigned)col;
                if (pk < mn1[rg]) { mn2[rg] = mn1[rg]; mn1[rg] = pk; }
                else if (pk < mn2[rg]) { mn2[rg] = pk; }
                qu_l[drow_base + rg][col] = (unsigned char)(qu * 255.f + 0.5f);
            }
        }
    }

    // ---- row reductions within wave, then merge the 2 N-halves ----
    #pragma unroll
    for (int rg = 0; rg < 4; ++rg) {
        float q = qs[rg];
        unsigned m = mn1[rg];
        #pragma unroll
        for (int mk = 1; mk < 16; mk <<= 1) {
            q += __shfl_xor(q, mk, 64);
            unsigned o = __shfl_xor(m, mk, 64);
            m = o < m ? o : m;
        }
        if ((lane & 15) == 0) {
            int row = drow_base + rg;
            qred[row][nthalf] = q;
            mred[row][nthalf] = m;
        }
    }
    __syncthreads();

    if (tid < MROWS) {
        int r = tid;
        float q = qred[r][0] + qred[r][1];
        unsigned m = mred[r][0] < mred[r][1] ? mred[r][0] : mred[r][1];
        dmin2_s[r] = __uint_as_float(m & ~1023u);   // truncated min d2 (<= true)
        qinv_s[r]  = 1.f / q;
    }
    __syncthreads();

    // ---- candidate gather from per-lane top-2 (u32 keys) ----
    #pragma unroll
    for (int rg = 0; rg < 4; ++rg) {
        int row = drow_base + rg;
        float lim = dmin2_s[row] + MARGIN;
        #pragma unroll
        for (int u = 0; u < 2; ++u) {
            unsigned mm = u ? mn2[rg] : mn1[rg];
            float d2v = __uint_as_float(mm & ~1023u);
            if (d2v < lim) {
                int sl = atomicAdd(&cnt_s[row], 1);
                if (sl < NCAND) cand_s[row][sl] = (int)(mm & 1023u);
            }
        }
    }
    __syncthreads();

    // ---- normalized q write FIRST (stores drain under the f64 refine below) ----
    float4* q4 = (float4*)(out + OFF_Q + (size_t)row0 * G_);
    #pragma unroll 8
    for (int i = 0; i < 32; ++i) {
        int p = i * 256 + tid;          // 8192 float4 of 32x1024
        int row = p >> 8, g = p & 255;
        float qi255 = qinv_s[row] * (1.f / 255.f);
        uchar4 qb = *(const uchar4*)&qu_l[row][4 * g];
        float4 v;
        v.x = (float)qb.x * qi255; v.y = (float)qb.y * qi255;
        v.z = (float)qb.z * qi255; v.w = (float)qb.w * qi255;
        q4[p] = v;
    }

    // ---- f64 re-rank of the candidate set (np-f64 emulation; nsq64 precomputed) ----
    {
        const int r = tid >> 3;
        const int s = tid & 7;
        const int cnt = cnt_s[r] < NCAND ? cnt_s[r] : NCAND;
        const int row = row0 + r;
        const double w64 = (double)tw_s[r] * (double)mk_s[r];
        const float* zp = z + (size_t)row * D_;
        double bs = 1e300; int bc = 0x7FFFFFFF;
        for (int i = s; i < cnt; i += 8) {
            const int c = cand_s[r][i];
            const float* nc = nodes + (size_t)c * D_;
            double dot = 0.0;
            for (int k = 0; k < D_; ++k) {
                double zw = (double)zp[k] * w64;
                dot = fma(zw, (double)nc[k], dot);
            }
            double sc = nsq64_g[c] - 2.0 * dot;
            if (sc < bs || (sc == bs && c < bc)) { bs = sc; bc = c; }
        }
        #pragma unroll
        for (int mm = 1; mm < 8; mm <<= 1) {
            double os = __shfl_xor(bs, mm, 64);
            int    oc = __shfl_xor(bc, mm, 64);
            if (os < bs || (os == bs && oc < bc)) { bs = os; bc = oc; }
        }
        if (s == 0) {
            bmu_s[r] = bc;
            out[OFF_BMU + row]       = (float)bc;
            out[OFF_KC + 2*row]      = (float)(bc >> 5);
            out[OFF_KC + 2*row + 1]  = (float)(bc & 31);
        }
    }
    __syncthreads();

    // ---- som_z = z + 0.1*(nodes[bmu] - z)*mask ----
    const float4* zr4 = (const float4*)(z + (size_t)row0 * D_);
    float4* so4 = (float4*)(out + OFF_SOMZ + (size_t)row0 * D_);
    #pragma unroll 4
    for (int i = 0; i < 8; ++i) {
        int p  = i * 256 + tid;
        int r  = p >> 6;
        int k4 = p & 63;
        float4 zv = zr4[p];
        float4 nn = ((const float4*)(nodes + (size_t)bmu_s[r] * D_))[k4];
        float m = 0.1f * mk_s[r];
        float4 o;
        o.x = zv.x + m * (nn.x - zv.x);
        o.y = zv.y + m * (nn.y - zv.y);
        o.z = zv.z + m * (nn.z - zv.z);
        o.w = zv.w + m * (nn.w - zv.w);
        so4[p] = o;
    }
}

// ---------------- fallback (round-10 verified f32 path, no workspace) ----------------
#define ROWS16(M) M(0) M(1) M(2) M(3) M(4) M(5) M(6) M(7) \
                  M(8) M(9) M(10) M(11) M(12) M(13) M(14) M(15)

__device__ __forceinline__ float qcomp_fb(float zq, float dot, float nsq,
                                          u64& mn, int col) {
    float d2   = zq - 2.f * dot + nsq;
    float dist = sqrtf(fmaxf(d2, 1e-12f));
    u64 pk = ((u64)__float_as_uint(dist) << 32) | (unsigned)col;
    mn = pk < mn ? pk : mn;
    return 1.f / (1.f + dist);
}

__global__ void som_fb(const float* __restrict__ z,
                       const float* __restrict__ mask,
                       const float* __restrict__ nodes,
                       float* __restrict__ out) {
    __shared__ __align__(16) float zl[RPB][D_];
    __shared__ float zsq_s[RPB], mk_s[RPB], tw_s[RPB], qinv_s[RPB], dmin2_s[RPB];
    __shared__ int   bmu_s[RPB], cnt_s[RPB], cand_s[RPB][NCAND];
    __shared__ u64   mred[RPB][4];
    __shared__ float qred[RPB][4];

    const int tid  = threadIdx.x;
    const int lane = tid & 63;
    const int wave = tid >> 6;
    const int row0 = blockIdx.x * RPB;
    const int b    = row0 / T_;
    const int t0   = row0 % T_;

    if (tid < RPB) {
        int t = t0 + tid;
        mk_s[tid] = mask[b * T_ + t];
        tw_s[tid] = (float)pow((double)0.999f, (double)(T_ - 1 - t));
        cnt_s[tid] = 0;
    }
    __syncthreads();

    const float4* z4 = (const float4*)(z + (size_t)row0 * D_);
    float4* zl4 = (float4*)zl;
    #pragma unroll
    for (int i = 0; i < 4; ++i) {
        int p = i * 256 + tid;
        int r = p >> 6;
        float tw = tw_s[r], m = mk_s[r];
        float4 v = z4[p];
        v.x = __fmul_rn(__fmul_rn(v.x, tw), m);
        v.y = __fmul_rn(__fmul_rn(v.y, tw), m);
        v.z = __fmul_rn(__fmul_rn(v.z, tw), m);
        v.w = __fmul_rn(__fmul_rn(v.w, tw), m);
        zl4[p] = v;
        float s = v.x*v.x + v.y*v.y + v.z*v.z + v.w*v.w;
        #pragma unroll
        for (int mm = 32; mm; mm >>= 1) s += __shfl_xor(s, mm, 64);
        if (lane == 0) zsq_s[r] = s;
    }
    __syncthreads();

#define DECL_ACC(i) float4 a##i = {0.f, 0.f, 0.f, 0.f};
    ROWS16(DECL_ACC)
#undef DECL_ACC
    float4 nss = {0.f, 0.f, 0.f, 0.f};
    const float4* nd4 = (const float4*)nodes;
    for (int k4 = 0; k4 < 64; ++k4) {
        float4 c0 = nd4[(4*tid + 0) * 64 + k4];
        float4 c1 = nd4[(4*tid + 1) * 64 + k4];
        float4 c2 = nd4[(4*tid + 2) * 64 + k4];
        float4 c3 = nd4[(4*tid + 3) * 64 + k4];
        nss.x += c0.x*c0.x + c0.y*c0.y + c0.z*c0.z + c0.w*c0.w;
        nss.y += c1.x*c1.x + c1.y*c1.y + c1.z*c1.z + c1.w*c1.w;
        nss.z += c2.x*c2.x + c2.y*c2.y + c2.z*c2.z + c2.w*c2.w;
        nss.w += c3.x*c3.x + c3.y*c3.y + c3.z*c3.z + c3.w*c3.w;
#define RFB(i) { float4 zv = zl4[(i) * 64 + k4];                                              \
        a##i.x = fmaf(zv.x, c0.x, fmaf(zv.y, c0.y, fmaf(zv.z, c0.z, fmaf(zv.w, c0.w, a##i.x)))); \
        a##i.y = fmaf(zv.x, c1.x, fmaf(zv.y, c1.y, fmaf(zv.z, c1.z, fmaf(zv.w, c1.w, a##i.y)))); \
        a##i.z = fmaf(zv.x, c2.x, fmaf(zv.y, c2.y, fmaf(zv.z, c2.z, fmaf(zv.w, c2.w, a##i.z)))); \
        a##i.w = fmaf(zv.x, c3.x, fmaf(zv.y, c3.y, fmaf(zv.z, c3.z, fmaf(zv.w, c3.w, a##i.w)))); }
        ROWS16(RFB)
#undef RFB
    }

#define EPI(i) { float zq = zsq_s[i]; u64 mn = ~0ULL;                       \
        a##i.x = qcomp_fb(zq, a##i.x, nss.x, mn, 4*tid + 0);                \
        a##i.y = qcomp_fb(zq, a##i.y, nss.y, mn, 4*tid + 1);                \
        a##i.z = qcomp_fb(zq, a##i.z, nss.z, mn, 4*tid + 2);                \
        a##i.w = qcomp_fb(zq, a##i.w, nss.w, mn, 4*tid + 3);                \
        float qs = a##i.x + a##i.y + a##i.z + a##i.w;                       \
        _Pragma("unroll")                                                   \
        for (int mm = 32; mm; mm >>= 1) {                                   \
            qs += __shfl_xor(qs, mm, 64);                                   \
            u64 o1 = __shfl_xor(mn, mm, 64);                                \
            mn = o1 < mn ? o1 : mn;                                         \
        }                                                                   \
        if (lane == 0) { qred[i][wave] = qs; mred[i][wave] = mn; } }
    ROWS16(EPI)
#undef EPI
    __syncthreads();

    if (tid < RPB) {
        int r = tid;
        float qs = qred[r][0] + qred[r][1] + qred[r][2] + qred[r][3];
        u64 mn1 = mred[r][0];
        mn1 = mred[r][1] < mn1 ? mred[r][1] : mn1;
        mn1 = mred[r][2] < mn1 ? mred[r][2] : mn1;
        mn1 = mred[r][3] < mn1 ? mred[r][3] : mn1;
        float dmin = __uint_as_float((unsigned)(mn1 >> 32));
        dmin2_s[r] = dmin * dmin;
        qinv_s[r]  = 1.f / qs;
    }
    __syncthreads();

#define GC(QU, COL, LIM, RI) { float dr = 1.f / (QU) - 1.f;                 \
        if (dr * dr < (LIM)) { int sl = atomicAdd(&cnt_s[RI], 1);           \
            if (sl < NCAND) cand_s[RI][sl] = (COL); } }
#define GTH(i) { float lim = dmin2_s[i] + MARGIN_FB;                        \
        GC(a##i.x, 4*tid + 0, lim, i) GC(a##i.y, 4*tid + 1, lim, i)         \
        GC(a##i.z, 4*tid + 2, lim, i) GC(a##i.w, 4*tid + 3, lim, i) }
    ROWS16(GTH)
#undef GTH
#undef GC

    float4* q4 = (float4*)(out + OFF_Q + (size_t)row0 * G_);
#define WRQ(i) { float qi = qinv_s[i]; float4 v;                            \
        v.x = a##i.x * qi; v.y = a##i.y * qi;                               \
        v.z = a##i.z * qi; v.w = a##i.w * qi;                               \
        q4[(i) * 256 + tid] = v; }
    ROWS16(WRQ)
#undef WRQ
    __syncthreads();

    {
        const int r = tid >> 4;
        const int s = tid & 15;
        const int cnt = cnt_s[r] < NCAND ? cnt_s[r] : NCAND;
        const int row = row0 + r;
        const double w64 = (double)tw_s[r] * (double)mk_s[r];
        const float* zp = z + (size_t)row * D_;
        double bs = 1e300; int bc = 0x7FFFFFFF;
        for (int i = s; i < cnt; i += 16) {
            const int c = cand_s[r][i];
            const float* nc = nodes + (size_t)c * D_;
            double dot = 0.0, nsqd = 0.0;
            for (int k = 0; k < D_; ++k) {
                double zw = (double)zp[k] * w64;
                double nv = (double)nc[k];
                dot  = fma(zw, nv, dot);
                nsqd = fma(nv, nv, nsqd);
            }
            double sc = nsqd - 2.0 * dot;
            if (sc < bs || (sc == bs && c < bc)) { bs = sc; bc = c; }
        }
        #pragma unroll
        for (int mm = 1; mm < 16; mm <<= 1) {
            double os = __shfl_xor(bs, mm, 64);
            int    oc = __shfl_xor(bc, mm, 64);
            if (os < bs || (os == bs && oc < bc)) { bs = os; bc = oc; }
        }
        if (s == 0) {
            bmu_s[r] = bc;
            out[OFF_BMU + row]       = (float)bc;
            out[OFF_KC + 2*row]      = (float)(bc >> 5);
            out[OFF_KC + 2*row + 1]  = (float)(bc & 31);
        }
    }
    __syncthreads();

    const float4* zr4 = (const float4*)(z + (size_t)row0 * D_);
    float4* so4 = (float4*)(out + OFF_SOMZ + (size_t)row0 * D_);
    #pragma unroll
    for (int i = 0; i < 4; ++i) {
        int p  = i * 256 + tid;
        int r  = p >> 6;
        int k4 = p & 63;
        float4 zv = zr4[p];
        float4 nn = ((const float4*)(nodes + (size_t)bmu_s[r] * D_))[k4];
        float m = 0.1f * mk_s[r];
        float4 o;
        o.x = zv.x + m * (nn.x - zv.x);
        o.y = zv.y + m * (nn.y - zv.y);
        o.z = zv.z + m * (nn.z - zv.z);
        o.w = zv.w + m * (nn.w - zv.w);
        so4[p] = o;
    }
}

extern "C" void kernel_launch(void* const* d_in, const int* in_sizes, int n_in,
                              void* d_out, int out_size, void* d_ws, size_t ws_size,
                              hipStream_t stream) {
    const float* z     = (const float*)d_in[0];
    const float* mask  = (const float*)d_in[1];
    const float* nodes = (const float*)d_in[2];
    float* out = (float*)d_out;

    const size_t bh_bytes = (size_t)G_ * D_ * 2;            // 512 KB
    const size_t n64_off  = bh_bytes;                        // 8-byte aligned
    const size_t n32_off  = n64_off + (size_t)G_ * sizeof(double);
    const size_t need     = n32_off + (size_t)G_ * sizeof(float);   // ~524 KB
    if (ws_size >= need) {
        short*  bh    = (short*)d_ws;
        double* nsq64 = (double*)((char*)d_ws + n64_off);
        float*  nsq   = (float*)((char*)d_ws + n32_off);
        prep_mx<<<G_ / 4, 256, 0, stream>>>(nodes, bh, nsq, nsq64);
        som_mfma<<<BT_ / MROWS, 256, 0, stream>>>(z, mask, nodes, bh, nsq, nsq64, out);
    } else {
        som_fb<<<BT_ / RPB, 256, 0, stream>>>(z, mask, nodes, out);
    }
}